// Round 1
// baseline (1161.062 us; speedup 1.0000x reference)
//
#include <hip/hip_runtime.h>

typedef __attribute__((ext_vector_type(8))) short short8;
typedef __attribute__((ext_vector_type(4))) float f32x4;

// ---------- helpers ----------
__device__ __forceinline__ unsigned short f2bf(float f) {
    union { float f; unsigned int u; } v; v.f = f;
    unsigned int u = v.u;
    unsigned int r = (u + 0x7FFFu + ((u >> 16) & 1u)) >> 16;
    return (unsigned short)r;
}
__device__ __forceinline__ float bf2f(unsigned short u) {
    union { unsigned int u; float f; } v; v.u = ((unsigned int)u) << 16;
    return v.f;
}
__device__ __forceinline__ void load_lds16(const void* g, void* l) {
    __builtin_amdgcn_global_load_lds(
        (const __attribute__((address_space(1))) void*)g,
        (__attribute__((address_space(3))) void*)l, 16, 0, 0);
}

// ---------- fp32 -> bf16 convert ----------
__global__ __launch_bounds__(256) void conv_bf16(const float* __restrict__ in,
                                                 unsigned short* __restrict__ out, int n4) {
    int i = blockIdx.x * 256 + threadIdx.x;
    if (i >= n4) return;
    float4 v = ((const float4*)in)[i];
    ushort4 o;
    o.x = f2bf(v.x); o.y = f2bf(v.y); o.z = f2bf(v.z); o.w = f2bf(v.w);
    ((ushort4*)out)[i] = o;
}

// ---------- GEMM  C[M,N] = A[M,K] * B[N,K]^T  (bt-form, bf16 in, fp32 acc) ----------
template <bool OUT_BF16>
__global__ __launch_bounds__(256) void gemm_bt(const unsigned short* __restrict__ A,
                                               const unsigned short* __restrict__ B,
                                               void* __restrict__ Cv, int M, int N, int K) {
    __shared__ __align__(16) unsigned short As[128 * 32];
    __shared__ __align__(16) unsigned short Bs[128 * 32];
    const int tid = threadIdx.x, lane = tid & 63, wv = tid >> 6;
    const int bn = blockIdx.x, bm = blockIdx.y;
    const int wr = (wv >> 1) * 64, wc = (wv & 1) * 64;
    const int fr = lane & 15, fo = (lane >> 4) * 8;
    f32x4 acc[4][4] = {};
    const unsigned short* gA = A + (size_t)(bm * 128) * K;
    const unsigned short* gB = B + (size_t)(bn * 128) * K;
    const int srow = wv * 32 + (lane >> 2);
    const int scol = (lane & 3) * 8;
    for (int kt = 0; kt < K; kt += 32) {
#pragma unroll
        for (int i = 0; i < 2; ++i) {
            load_lds16(&gA[(size_t)(srow + i * 16) * K + kt + scol], &As[(wv * 32 + i * 16) * 32]);
            load_lds16(&gB[(size_t)(srow + i * 16) * K + kt + scol], &Bs[(wv * 32 + i * 16) * 32]);
        }
        __syncthreads();
        short8 a[4], b[4];
#pragma unroll
        for (int m = 0; m < 4; ++m) a[m] = *(const short8*)&As[(wr + m * 16 + fr) * 32 + fo];
#pragma unroll
        for (int n = 0; n < 4; ++n) b[n] = *(const short8*)&Bs[(wc + n * 16 + fr) * 32 + fo];
#pragma unroll
        for (int m = 0; m < 4; ++m)
#pragma unroll
            for (int n = 0; n < 4; ++n)
                acc[m][n] = __builtin_amdgcn_mfma_f32_16x16x32_bf16(a[m], b[n], acc[m][n], 0, 0, 0);
        __syncthreads();
    }
    const size_t row0 = (size_t)bm * 128 + wr + ((lane >> 4) << 2);
    const int col0 = bn * 128 + wc + fr;
#pragma unroll
    for (int m = 0; m < 4; ++m)
#pragma unroll
        for (int n = 0; n < 4; ++n)
#pragma unroll
            for (int j = 0; j < 4; ++j) {
                size_t idx = (row0 + m * 16 + j) * (size_t)N + col0 + n * 16;
                if (OUT_BF16) ((unsigned short*)Cv)[idx] = f2bf(acc[m][n][j]);
                else          ((float*)Cv)[idx] = acc[m][n][j];
            }
}

// ---------- RoPE (interleaved, first 64 dims) + repack q,k -> [b,h,s,d] ----------
__global__ __launch_bounds__(256) void rope_repack(const unsigned short* __restrict__ qkv,
                                                   const int* __restrict__ positions,
                                                   unsigned short* __restrict__ qp,
                                                   unsigned short* __restrict__ kp) {
    int r = blockIdx.x * 4 + (threadIdx.x >> 6);   // (b,s,h) row, 0..65535
    int h = r & 15, s = (r >> 4) & 2047, b = r >> 15;
    int d = (threadIdx.x & 63) * 4;
    const unsigned short* src = qkv + (size_t)(b * 2048 + s) * 12288 + h * 256 + d;
    ushort4 q = *(const ushort4*)src;
    ushort4 k = *(const ushort4*)(src + 4096);
    if (d < 64) {
        float pos = (float)positions[s];
        const float LF = 0.4152410118609203f;      // log2(10000)/32
        float i0 = (float)(d >> 1);
        float a0 = pos * exp2f(-i0 * LF);
        float a1 = pos * exp2f(-(i0 + 1.0f) * LF);
        float c0 = cosf(a0), s0 = sinf(a0), c1 = cosf(a1), s1 = sinf(a1);
        float qx = bf2f(q.x), qy = bf2f(q.y), qz = bf2f(q.z), qw = bf2f(q.w);
        q.x = f2bf(qx * c0 - qy * s0); q.y = f2bf(qx * s0 + qy * c0);
        q.z = f2bf(qz * c1 - qw * s1); q.w = f2bf(qz * s1 + qw * c1);
        float kx = bf2f(k.x), ky = bf2f(k.y), kz = bf2f(k.z), kw = bf2f(k.w);
        k.x = f2bf(kx * c0 - ky * s0); k.y = f2bf(kx * s0 + ky * c0);
        k.z = f2bf(kz * c1 - kw * s1); k.w = f2bf(kz * s1 + kw * c1);
    }
    size_t dst = ((size_t)((b * 16 + h) * 2048 + s)) * 256 + d;
    *(ushort4*)&qp[dst] = q;
    *(ushort4*)&kp[dst] = k;
}

// ---------- V transpose -> [b,h,d,s] ----------
__global__ __launch_bounds__(256) void v_transpose(const unsigned short* __restrict__ qkv,
                                                   unsigned short* __restrict__ vt) {
    int bid = blockIdx.x;
    int dt = bid & 3, st = (bid >> 2) & 31, bh = bid >> 7;
    int b = bh >> 4, h = bh & 15;
    __shared__ unsigned short t[64][72];
    int tid = threadIdx.x;
#pragma unroll
    for (int rep = 0; rep < 16; ++rep) {
        int idx = rep * 256 + tid;
        int r = idx >> 6, c = idx & 63;   // r: s-offset, c: d-offset
        t[r][c] = qkv[(size_t)(b * 2048 + st * 64 + r) * 12288 + 8192 + h * 256 + dt * 64 + c];
    }
    __syncthreads();
#pragma unroll
    for (int rep = 0; rep < 16; ++rep) {
        int idx = rep * 256 + tid;
        int r = idx >> 6, c = idx & 63;   // r: d-offset, c: s-offset
        vt[(size_t)(bh * 256 + dt * 64 + r) * 2048 + st * 64 + c] = t[c][r];
    }
}

// ---------- flash attention (causal), 4 waves x 16 q-rows, KV tile 32 ----------
__global__ __launch_bounds__(256) void attn_fwd(const unsigned short* __restrict__ Qp,
                                                const unsigned short* __restrict__ Kp,
                                                const unsigned short* __restrict__ Vt,
                                                unsigned short* __restrict__ Oa) {
    __shared__ __align__(16) unsigned short Ks[32 * 256];
    __shared__ __align__(16) unsigned short Vs[256 * 32];
    __shared__ __align__(16) unsigned short Ps[4][16 * 32];
    const int tid = threadIdx.x, lane = tid & 63, wv = tid >> 6;
    const int bh = blockIdx.x, qt = blockIdx.y;
    const int fr = lane & 15, fo = (lane >> 4) * 8;
    const unsigned short* Qb = Qp + (size_t)bh * 2048 * 256;
    const unsigned short* Kb = Kp + (size_t)bh * 2048 * 256;
    const unsigned short* Vb = Vt + (size_t)bh * 256 * 2048;
    const int qbase = qt * 64 + wv * 16;

    short8 qf[8];
#pragma unroll
    for (int c = 0; c < 8; ++c)
        qf[c] = *(const short8*)&Qb[(size_t)(qbase + fr) * 256 + c * 32 + fo];

    f32x4 o_acc[16] = {};
    float m_run[4] = {-1e30f, -1e30f, -1e30f, -1e30f};
    float l_run[4] = {0.f, 0.f, 0.f, 0.f};

    const int nkv = qt * 64 + 64;
    for (int kv0 = 0; kv0 < nkv; kv0 += 32) {
        // stage K tile [32][256] and V^T tile [256][32] (16 KB each)
#pragma unroll
        for (int i = 0; i < 4; ++i) {
            int eb = (wv * 4 + i) * 512;
            load_lds16(&Kb[(size_t)(kv0 + (eb >> 8) + (lane >> 5)) * 256 + (lane & 31) * 8], &Ks[eb]);
        }
#pragma unroll
        for (int i = 0; i < 4; ++i) {
            int eb = (wv * 4 + i) * 512;
            load_lds16(&Vb[(size_t)((eb >> 5) + (lane >> 2)) * 2048 + kv0 + (lane & 3) * 8], &Vs[eb]);
        }
        __syncthreads();

        // scores: two 16x16 kv tiles, K-dim = head_dim 256
        f32x4 sc[2] = {};
#pragma unroll
        for (int t = 0; t < 2; ++t)
#pragma unroll
            for (int c = 0; c < 8; ++c) {
                short8 kf = *(const short8*)&Ks[(t * 16 + fr) * 256 + c * 32 + fo];
                sc[t] = __builtin_amdgcn_mfma_f32_16x16x32_bf16(qf[c], kf, sc[t], 0, 0, 0);
            }

        // online softmax (D layout: col = lane&15 = kv, row = (lane>>4)*4+j = q)
        float sv[2][4];
#pragma unroll
        for (int j = 0; j < 4; ++j) {
            int qi = qbase + ((lane >> 4) << 2) + j;
#pragma unroll
            for (int t = 0; t < 2; ++t) {
                float x = sc[t][j] * 0.0625f;
                int kvi = kv0 + t * 16 + fr;
                sv[t][j] = (kvi > qi) ? -1e30f : x;
            }
            float pm = fmaxf(sv[0][j], sv[1][j]);
#pragma unroll
            for (int off = 1; off < 16; off <<= 1)
                pm = fmaxf(pm, __shfl_xor(pm, off));
            float mn = fmaxf(m_run[j], pm);
            float al = __expf(m_run[j] - mn);
            m_run[j] = mn;
            float rs = 0.f;
#pragma unroll
            for (int t = 0; t < 2; ++t) {
                float p = __expf(sv[t][j] - mn);
                rs += p;
                Ps[wv][(((lane >> 4) << 2) + j) * 32 + t * 16 + fr] = f2bf(p);
            }
#pragma unroll
            for (int off = 1; off < 16; off <<= 1)
                rs += __shfl_xor(rs, off);
            l_run[j] = l_run[j] * al + rs;
#pragma unroll
            for (int n = 0; n < 16; ++n) o_acc[n][j] *= al;
        }

        // PV: P (16x32) x V^T-tiles -> 16 d-tiles
        short8 pf = *(const short8*)&Ps[wv][fr * 32 + fo];
#pragma unroll
        for (int n = 0; n < 16; ++n) {
            short8 vf = *(const short8*)&Vs[(n * 16 + fr) * 32 + fo];
            o_acc[n] = __builtin_amdgcn_mfma_f32_16x16x32_bf16(pf, vf, o_acc[n], 0, 0, 0);
        }
        __syncthreads();
    }

    // epilogue: divide by l, write [b, s, h*256+d] bf16
    const int b = bh >> 4, h = bh & 15;
#pragma unroll
    for (int j = 0; j < 4; ++j) {
        float inv = 1.0f / l_run[j];
        int qrow = qbase + ((lane >> 4) << 2) + j;
        size_t base = ((size_t)(b * 2048 + qrow)) * 4096 + h * 256;
#pragma unroll
        for (int n = 0; n < 16; ++n)
            Oa[base + n * 16 + fr] = f2bf(o_acc[n][j] * inv);
    }
}

// ---------- launch ----------
extern "C" void kernel_launch(void* const* d_in, const int* in_sizes, int n_in,
                              void* d_out, int out_size, void* d_ws, size_t ws_size,
                              hipStream_t stream) {
    const float* hidden = (const float*)d_in[0];
    const int* positions = (const int*)d_in[1];
    const float* w_qkv = (const float*)d_in[2];
    const float* w_out = (const float*)d_in[3];
    float* out = (float*)d_out;

    const size_t MB32 = 33554432;   // 32 MiB
    char* ws = (char*)d_ws;
    unsigned short* hidden_bf = (unsigned short*)ws;              // 32 MB; later attn out
    unsigned short* wqkv_bf   = (unsigned short*)(ws + MB32);     // 96 MB; later q/k/vt
    unsigned short* qkv_bf    = (unsigned short*)(ws + 4 * MB32); // 96 MB; later wout_bf
    unsigned short* qp  = wqkv_bf;                                // 32 MB
    unsigned short* kp  = wqkv_bf + 16777216;                     // 32 MB
    unsigned short* vtp = wqkv_bf + 33554432;                     // 32 MB
    unsigned short* attn_bf = hidden_bf;                          // 32 MB (reuse)
    unsigned short* wout_bf = qkv_bf;                             // 32 MB (reuse)

    // 1. convert hidden (16.7M) and w_qkv (50.3M) to bf16
    conv_bf16<<<16384, 256, 0, stream>>>(hidden, hidden_bf, 4194304);
    conv_bf16<<<49152, 256, 0, stream>>>(w_qkv, wqkv_bf, 12582912);

    // 2. qkv = hidden @ w_qkv^T   (M=4096, N=12288, K=4096), bf16 out
    gemm_bt<true><<<dim3(96, 32), 256, 0, stream>>>(hidden_bf, wqkv_bf, qkv_bf, 4096, 12288, 4096);

    // 3. RoPE + repack q,k ; transpose v
    rope_repack<<<16384, 256, 0, stream>>>(qkv_bf, positions, qp, kp);
    v_transpose<<<4096, 256, 0, stream>>>(qkv_bf, vtp);

    // 4. causal flash attention -> attn_bf [4096, 4096]
    attn_fwd<<<dim3(32, 32), 256, 0, stream>>>(qp, kp, vtp, attn_bf);

    // 5. convert w_out, final projection (fp32 out)
    conv_bf16<<<16384, 256, 0, stream>>>(w_out, wout_bf, 4194304);
    gemm_bt<false><<<dim3(32, 32), 256, 0, stream>>>(attn_bf, wout_bf, out, 4096, 4096, 4096);
}

// Round 2
// 896.880 us; speedup vs baseline: 1.2946x; 1.2946x over previous
//
#include <hip/hip_runtime.h>

typedef __attribute__((ext_vector_type(8))) short short8;
typedef __attribute__((ext_vector_type(4))) float f32x4;

// ---------- helpers ----------
__device__ __forceinline__ unsigned short f2bf(float f) {
    union { float f; unsigned int u; } v; v.f = f;
    unsigned int u = v.u;
    unsigned int r = (u + 0x7FFFu + ((u >> 16) & 1u)) >> 16;
    return (unsigned short)r;
}
__device__ __forceinline__ float bf2f(unsigned short u) {
    union { unsigned int u; float f; } v; v.u = ((unsigned int)u) << 16;
    return v.f;
}
__device__ __forceinline__ void load_lds16(const void* g, void* l) {
    __builtin_amdgcn_global_load_lds(
        (const __attribute__((address_space(1))) void*)g,
        (__attribute__((address_space(3))) void*)l, 16, 0, 0);
}
#define FENCE() asm volatile("" ::: "memory")
#define BAR() do { FENCE(); __builtin_amdgcn_s_barrier(); FENCE(); } while (0)

// ---------- fp32 -> bf16 convert ----------
__global__ __launch_bounds__(256) void conv_bf16(const float* __restrict__ in,
                                                 unsigned short* __restrict__ out, int n4) {
    int i = blockIdx.x * 256 + threadIdx.x;
    if (i >= n4) return;
    float4 v = ((const float4*)in)[i];
    ushort4 o;
    o.x = f2bf(v.x); o.y = f2bf(v.y); o.z = f2bf(v.z); o.w = f2bf(v.w);
    ((ushort4*)out)[i] = o;
}

// ---------- 256x256 8-phase GEMM  C[M,N] = A[M,K] * B[N,K]^T (bf16 in, fp32 acc) ----
// Geometry: BM=BN=256, BK=64, 8 waves (2M x 4N), per-wave out 128x64.
// LDS 128 KiB: buf b at b*65536; A tile (256x64 bf16, 32 KB) at +0, B at +32768.
// st_16x32 swizzle: byte ^= ((byte>>9)&1)<<5 within the 32KB tile; staged with
// linear LDS dest + inverse-swizzled (involution) global source, read swizzled.
// Stage schedule (iter i computes t0=2i from buf0 p1-4, t1=2i+1 from buf1 p5-8):
//   p1: A-h0(t1->buf1)   [buf1-A last read prev p7, retired by prev p7-end bar]
//   p2: A-h1(t1->buf1)
//   p3: B-h0(t0+2->buf0) [buf0-B read p1/p2, retired by p2-end bar]
//   p4: B-h1(t0+2->buf0)
//   p5: A-h0(t0+2->buf0) [buf0-A read p1/p3, retired by p3-end bar]
//   p6: A-h1(t0+2->buf0)
//   p7: B-h0(t1+2->buf1) [buf1-B read p5/p6, retired by p6-end bar]
//   p8: B-h1(t1+2->buf1)
// vmcnt(4) before p4-end barrier => t1 fully landed before p5 reads.
// vmcnt(4) before p8-end barrier => t0+2 fully landed before next p1 reads.
// Last iteration: p1/p2 stage only, vmcnt(0) at p4, nothing at p8.
template <bool OUT_BF16>
__global__ __launch_bounds__(512, 2) void gemm256(const unsigned short* __restrict__ A,
                                                  const unsigned short* __restrict__ B,
                                                  void* __restrict__ Cv,
                                                  int M, int N, int K, int NBN) {
    __shared__ __align__(16) char smem[131072];
    const int tid = threadIdx.x;
    const int lane = tid & 63, wv = tid >> 6;
    const int wm = wv >> 2, wn = wv & 3;
    const int fr = lane & 15, fo = (lane >> 4) * 8;

    // bijective XCD swizzle (m204)
    const int nwg = gridDim.x, bid = blockIdx.x;
    const int q = nwg >> 3, r = nwg & 7, xcd = bid & 7, lid = bid >> 3;
    const int wg = (xcd < r ? xcd * (q + 1) : r * (q + 1) + (xcd - r) * q) + lid;
    const int bm = wg / NBN, bn = wg % NBN;

    const unsigned short* gA = A + (size_t)bm * 256 * K;
    const unsigned short* gB = B + (size_t)bn * 256 * K;

    // staging geometry: linear LDS dest o -> global element at swz(o)
    int srow[2][2], scol[2][2];
#pragma unroll
    for (int h = 0; h < 2; ++h)
#pragma unroll
        for (int rr = 0; rr < 2; ++rr) {
            int o = h * 16384 + rr * 8192 + tid * 16;
            int osw = o ^ ((o & 0x200) >> 4);
            srow[h][rr] = osw >> 7;
            scol[h][rr] = (osw & 127) >> 1;
        }

    f32x4 acc[8][4] = {};
    short8 a[4][2], b[4][2];

    auto STAGE = [&](const unsigned short* g, int regionBase, int h, int t) {
#pragma unroll
        for (int rr = 0; rr < 2; ++rr)
            load_lds16(g + (size_t)srow[h][rr] * K + t * 64 + scol[h][rr],
                       smem + regionBase + h * 16384 + rr * 8192 + tid * 16);
    };
    auto RDA = [&](int bufBase, int mh) {
#pragma unroll
        for (int mf = 0; mf < 4; ++mf)
#pragma unroll
            for (int ks = 0; ks < 2; ++ks) {
                int o = (wm * 128 + mh * 64 + mf * 16 + fr) * 128 + (ks * 32 + fo) * 2;
                o ^= (o & 0x200) >> 4;
                a[mf][ks] = *(const short8*)(smem + bufBase + o);
            }
    };
    auto RDB = [&](int bufBase, int nh) {
#pragma unroll
        for (int jj = 0; jj < 2; ++jj)
#pragma unroll
            for (int ks = 0; ks < 2; ++ks) {
                int o = (wn * 64 + (nh * 2 + jj) * 16 + fr) * 128 + (ks * 32 + fo) * 2;
                o ^= (o & 0x200) >> 4;
                b[nh * 2 + jj][ks] = *(const short8*)(smem + bufBase + 32768 + o);
            }
    };
    auto MM = [&](int mh, int nh) {
        __builtin_amdgcn_s_setprio(1);
#pragma unroll
        for (int mf = 0; mf < 4; ++mf)
#pragma unroll
            for (int jj = 0; jj < 2; ++jj)
#pragma unroll
                for (int ks = 0; ks < 2; ++ks)
                    acc[mh * 4 + mf][nh * 2 + jj] = __builtin_amdgcn_mfma_f32_16x16x32_bf16(
                        a[mf][ks], b[nh * 2 + jj][ks], acc[mh * 4 + mf][nh * 2 + jj], 0, 0, 0);
        __builtin_amdgcn_s_setprio(0);
    };

    // region byte bases
    const int A0 = 0, B0 = 32768, A1 = 65536, B1 = 98304;

    // prologue: tile0 full into buf0, tile1 B-halves into buf1
    STAGE(gA, A0, 0, 0); STAGE(gA, A0, 1, 0);
    STAGE(gB, B0, 0, 0); STAGE(gB, B0, 1, 0);
    STAGE(gB, B1, 0, 1); STAGE(gB, B1, 1, 1);
    FENCE();
    asm volatile("s_waitcnt vmcnt(4)" ::: "memory");
    __builtin_amdgcn_s_barrier();
    FENCE();

    const int NIT = K >> 7;  // K/128, K%128==0
    for (int i = 0; i < NIT; ++i) {
        const bool last = (i == NIT - 1);
        const int t0 = 2 * i, t1 = 2 * i + 1;
        // P1
        RDA(A0, 0); RDB(A0, 0);
        STAGE(gA, A1, 0, t1);
        BAR(); MM(0, 0); BAR();
        // P2
        RDB(A0, 1);
        STAGE(gA, A1, 1, t1);
        BAR(); MM(0, 1); BAR();
        // P3
        RDA(A0, 1);
        if (!last) STAGE(gB, B0, 0, t0 + 2);
        BAR(); MM(1, 1); BAR();
        // P4
        if (!last) STAGE(gB, B0, 1, t0 + 2);
        BAR(); MM(1, 0);
        FENCE();
        if (last) asm volatile("s_waitcnt vmcnt(0)" ::: "memory");
        else      asm volatile("s_waitcnt vmcnt(4)" ::: "memory");
        __builtin_amdgcn_s_barrier();
        FENCE();
        // P5
        RDA(A1, 0); RDB(A1 /*buf1 base*/, 0);
        if (!last) STAGE(gA, A0, 0, t0 + 2);
        BAR(); MM(0, 0); BAR();
        // P6
        RDB(A1, 1);
        if (!last) STAGE(gA, A0, 1, t0 + 2);
        BAR(); MM(0, 1); BAR();
        // P7
        RDA(A1, 1);
        if (!last) STAGE(gB, B1, 0, t1 + 2);
        BAR(); MM(1, 1); BAR();
        // P8
        if (!last) STAGE(gB, B1, 1, t1 + 2);
        BAR(); MM(1, 0);
        FENCE();
        if (!last) asm volatile("s_waitcnt vmcnt(4)" ::: "memory");
        __builtin_amdgcn_s_barrier();
        FENCE();
    }

    // epilogue
    const size_t row0 = (size_t)bm * 256 + wm * 128 + ((lane >> 4) << 2);
    const int col0 = bn * 256 + wn * 64 + fr;
#pragma unroll
    for (int mf = 0; mf < 8; ++mf)
#pragma unroll
        for (int nf = 0; nf < 4; ++nf)
#pragma unroll
            for (int j = 0; j < 4; ++j) {
                size_t idx = (row0 + mf * 16 + j) * (size_t)N + col0 + nf * 16;
                if (OUT_BF16) ((unsigned short*)Cv)[idx] = f2bf(acc[mf][nf][j]);
                else          ((float*)Cv)[idx] = acc[mf][nf][j];
            }
}

// ---------- RoPE (interleaved, first 64 dims) + repack q,k -> [b,h,s,d] ----------
__global__ __launch_bounds__(256) void rope_repack(const unsigned short* __restrict__ qkv,
                                                   const int* __restrict__ positions,
                                                   unsigned short* __restrict__ qp,
                                                   unsigned short* __restrict__ kp) {
    int r = blockIdx.x * 4 + (threadIdx.x >> 6);   // (b,s,h) row, 0..65535
    int h = r & 15, s = (r >> 4) & 2047, b = r >> 15;
    int d = (threadIdx.x & 63) * 4;
    const unsigned short* src = qkv + (size_t)(b * 2048 + s) * 12288 + h * 256 + d;
    ushort4 q = *(const ushort4*)src;
    ushort4 k = *(const ushort4*)(src + 4096);
    if (d < 64) {
        float pos = (float)positions[s];
        const float LF = 0.4152410118609203f;      // log2(10000)/32
        float i0 = (float)(d >> 1);
        float a0 = pos * exp2f(-i0 * LF);
        float a1 = pos * exp2f(-(i0 + 1.0f) * LF);
        float c0 = cosf(a0), s0 = sinf(a0), c1 = cosf(a1), s1 = sinf(a1);
        float qx = bf2f(q.x), qy = bf2f(q.y), qz = bf2f(q.z), qw = bf2f(q.w);
        q.x = f2bf(qx * c0 - qy * s0); q.y = f2bf(qx * s0 + qy * c0);
        q.z = f2bf(qz * c1 - qw * s1); q.w = f2bf(qz * s1 + qw * c1);
        float kx = bf2f(k.x), ky = bf2f(k.y), kz = bf2f(k.z), kw = bf2f(k.w);
        k.x = f2bf(kx * c0 - ky * s0); k.y = f2bf(kx * s0 + ky * c0);
        k.z = f2bf(kz * c1 - kw * s1); k.w = f2bf(kz * s1 + kw * c1);
    }
    size_t dst = ((size_t)((b * 16 + h) * 2048 + s)) * 256 + d;
    *(ushort4*)&qp[dst] = q;
    *(ushort4*)&kp[dst] = k;
}

// ---------- V transpose -> [b,h,d,s] ----------
__global__ __launch_bounds__(256) void v_transpose(const unsigned short* __restrict__ qkv,
                                                   unsigned short* __restrict__ vt) {
    int bid = blockIdx.x;
    int dt = bid & 3, st = (bid >> 2) & 31, bh = bid >> 7;
    int b = bh >> 4, h = bh & 15;
    __shared__ unsigned short t[64][72];
    int tid = threadIdx.x;
#pragma unroll
    for (int rep = 0; rep < 16; ++rep) {
        int idx = rep * 256 + tid;
        int r = idx >> 6, c = idx & 63;   // r: s-offset, c: d-offset
        t[r][c] = qkv[(size_t)(b * 2048 + st * 64 + r) * 12288 + 8192 + h * 256 + dt * 64 + c];
    }
    __syncthreads();
#pragma unroll
    for (int rep = 0; rep < 16; ++rep) {
        int idx = rep * 256 + tid;
        int r = idx >> 6, c = idx & 63;   // r: d-offset, c: s-offset
        vt[(size_t)(bh * 256 + dt * 64 + r) * 2048 + st * 64 + c] = t[c][r];
    }
}

// ---------- flash attention (causal), 4 waves x 16 q-rows, KV tile 32 ----------
__global__ __launch_bounds__(256) void attn_fwd(const unsigned short* __restrict__ Qp,
                                                const unsigned short* __restrict__ Kp,
                                                const unsigned short* __restrict__ Vt,
                                                unsigned short* __restrict__ Oa) {
    __shared__ __align__(16) unsigned short Ks[32 * 256];
    __shared__ __align__(16) unsigned short Vs[256 * 32];
    __shared__ __align__(16) unsigned short Ps[4][16 * 32];
    const int tid = threadIdx.x, lane = tid & 63, wv = tid >> 6;
    const int bh = blockIdx.x, qt = blockIdx.y;
    const int fr = lane & 15, fo = (lane >> 4) * 8;
    const unsigned short* Qb = Qp + (size_t)bh * 2048 * 256;
    const unsigned short* Kb = Kp + (size_t)bh * 2048 * 256;
    const unsigned short* Vb = Vt + (size_t)bh * 256 * 2048;
    const int qbase = qt * 64 + wv * 16;

    short8 qf[8];
#pragma unroll
    for (int c = 0; c < 8; ++c)
        qf[c] = *(const short8*)&Qb[(size_t)(qbase + fr) * 256 + c * 32 + fo];

    f32x4 o_acc[16] = {};
    float m_run[4] = {-1e30f, -1e30f, -1e30f, -1e30f};
    float l_run[4] = {0.f, 0.f, 0.f, 0.f};

    const int nkv = qt * 64 + 64;
    for (int kv0 = 0; kv0 < nkv; kv0 += 32) {
#pragma unroll
        for (int i = 0; i < 4; ++i) {
            int eb = (wv * 4 + i) * 512;
            load_lds16(&Kb[(size_t)(kv0 + (eb >> 8) + (lane >> 5)) * 256 + (lane & 31) * 8], &Ks[eb]);
        }
#pragma unroll
        for (int i = 0; i < 4; ++i) {
            int eb = (wv * 4 + i) * 512;
            load_lds16(&Vb[(size_t)((eb >> 5) + (lane >> 2)) * 2048 + kv0 + (lane & 3) * 8], &Vs[eb]);
        }
        __syncthreads();

        f32x4 sc[2] = {};
#pragma unroll
        for (int t = 0; t < 2; ++t)
#pragma unroll
            for (int c = 0; c < 8; ++c) {
                short8 kf = *(const short8*)&Ks[(t * 16 + fr) * 256 + c * 32 + fo];
                sc[t] = __builtin_amdgcn_mfma_f32_16x16x32_bf16(qf[c], kf, sc[t], 0, 0, 0);
            }

        float sv[2][4];
#pragma unroll
        for (int j = 0; j < 4; ++j) {
            int qi = qbase + ((lane >> 4) << 2) + j;
#pragma unroll
            for (int t = 0; t < 2; ++t) {
                float x = sc[t][j] * 0.0625f;
                int kvi = kv0 + t * 16 + fr;
                sv[t][j] = (kvi > qi) ? -1e30f : x;
            }
            float pm = fmaxf(sv[0][j], sv[1][j]);
#pragma unroll
            for (int off = 1; off < 16; off <<= 1)
                pm = fmaxf(pm, __shfl_xor(pm, off));
            float mn = fmaxf(m_run[j], pm);
            float al = __expf(m_run[j] - mn);
            m_run[j] = mn;
            float rs = 0.f;
#pragma unroll
            for (int t = 0; t < 2; ++t) {
                float p = __expf(sv[t][j] - mn);
                rs += p;
                Ps[wv][(((lane >> 4) << 2) + j) * 32 + t * 16 + fr] = f2bf(p);
            }
#pragma unroll
            for (int off = 1; off < 16; off <<= 1)
                rs += __shfl_xor(rs, off);
            l_run[j] = l_run[j] * al + rs;
#pragma unroll
            for (int n = 0; n < 16; ++n) o_acc[n][j] *= al;
        }

        short8 pf = *(const short8*)&Ps[wv][fr * 32 + fo];
#pragma unroll
        for (int n = 0; n < 16; ++n) {
            short8 vf = *(const short8*)&Vs[(n * 16 + fr) * 32 + fo];
            o_acc[n] = __builtin_amdgcn_mfma_f32_16x16x32_bf16(pf, vf, o_acc[n], 0, 0, 0);
        }
        __syncthreads();
    }

    const int b = bh >> 4, h = bh & 15;
#pragma unroll
    for (int j = 0; j < 4; ++j) {
        float inv = 1.0f / l_run[j];
        int qrow = qbase + ((lane >> 4) << 2) + j;
        size_t base = ((size_t)(b * 2048 + qrow)) * 4096 + h * 256;
#pragma unroll
        for (int n = 0; n < 16; ++n)
            Oa[base + n * 16 + fr] = f2bf(o_acc[n][j] * inv);
    }
}

// ---------- launch ----------
extern "C" void kernel_launch(void* const* d_in, const int* in_sizes, int n_in,
                              void* d_out, int out_size, void* d_ws, size_t ws_size,
                              hipStream_t stream) {
    const float* hidden = (const float*)d_in[0];
    const int* positions = (const int*)d_in[1];
    const float* w_qkv = (const float*)d_in[2];
    const float* w_out = (const float*)d_in[3];
    float* out = (float*)d_out;

    const size_t MB32 = 33554432;   // 32 MiB
    char* ws = (char*)d_ws;
    unsigned short* hidden_bf = (unsigned short*)ws;              // 32 MB; later attn out
    unsigned short* wqkv_bf   = (unsigned short*)(ws + MB32);     // 96 MB; later q/k/vt
    unsigned short* qkv_bf    = (unsigned short*)(ws + 4 * MB32); // 96 MB; later wout_bf
    unsigned short* qp  = wqkv_bf;                                // 32 MB
    unsigned short* kp  = wqkv_bf + 16777216;                     // 32 MB
    unsigned short* vtp = wqkv_bf + 33554432;                     // 32 MB
    unsigned short* attn_bf = hidden_bf;                          // 32 MB (reuse)
    unsigned short* wout_bf = qkv_bf;                             // 32 MB (reuse)

    // 1. convert hidden (16.7M) and w_qkv (50.3M) to bf16
    conv_bf16<<<16384, 256, 0, stream>>>(hidden, hidden_bf, 4194304);
    conv_bf16<<<49152, 256, 0, stream>>>(w_qkv, wqkv_bf, 12582912);

    // 2. qkv = hidden @ w_qkv^T   (M=4096, N=12288, K=4096), bf16 out
    gemm256<true><<<16 * 48, 512, 0, stream>>>(hidden_bf, wqkv_bf, qkv_bf, 4096, 12288, 4096, 48);

    // 3. RoPE + repack q,k ; transpose v
    rope_repack<<<16384, 256, 0, stream>>>(qkv_bf, positions, qp, kp);
    v_transpose<<<4096, 256, 0, stream>>>(qkv_bf, vtp);

    // 4. causal flash attention -> attn_bf [4096, 4096]
    attn_fwd<<<dim3(32, 32), 256, 0, stream>>>(qp, kp, vtp, attn_bf);

    // 5. convert w_out, final projection (fp32 out)
    conv_bf16<<<16384, 256, 0, stream>>>(w_out, wout_bf, 4194304);
    gemm256<false><<<16 * 16, 512, 0, stream>>>(attn_bf, wout_bf, out, 4096, 4096, 4096, 16);
}

// Round 3
// 853.116 us; speedup vs baseline: 1.3610x; 1.0513x over previous
//
#include <hip/hip_runtime.h>

typedef __attribute__((ext_vector_type(8))) short short8;
typedef __attribute__((ext_vector_type(4))) float f32x4;

// ---------- helpers ----------
__device__ __forceinline__ unsigned short f2bf(float f) {
    union { float f; unsigned int u; } v; v.f = f;
    unsigned int u = v.u;
    unsigned int r = (u + 0x7FFFu + ((u >> 16) & 1u)) >> 16;
    return (unsigned short)r;
}
__device__ __forceinline__ float bf2f(unsigned short u) {
    union { unsigned int u; float f; } v; v.u = ((unsigned int)u) << 16;
    return v.f;
}
__device__ __forceinline__ void load_lds16(const void* g, void* l) {
    __builtin_amdgcn_global_load_lds(
        (const __attribute__((address_space(1))) void*)g,
        (__attribute__((address_space(3))) void*)l, 16, 0, 0);
}
#define FENCE() asm volatile("" ::: "memory")
#define BAR() do { FENCE(); __builtin_amdgcn_s_barrier(); FENCE(); } while (0)

// LDS swizzle: XOR row&7 (byte-offset bits 7-9 at 128B row stride) into the
// 16B-slot index (bits 4-6). Involution; maps 16B chunks to 16B chunks.
// For a ds_read_b128 wave access (fixed ks): slot = (ks*4+g) ^ (fr&7)
// -> 8 slots x 8 lanes covering all 32 banks = the 1024B/wave minimum.
__device__ __forceinline__ int swz(int o) { return o ^ ((o >> 3) & 0x70); }

// ---------- fp32 -> bf16 convert ----------
__global__ __launch_bounds__(256) void conv_bf16(const float* __restrict__ in,
                                                 unsigned short* __restrict__ out, int n4) {
    int i = blockIdx.x * 256 + threadIdx.x;
    if (i >= n4) return;
    float4 v = ((const float4*)in)[i];
    ushort4 o;
    o.x = f2bf(v.x); o.y = f2bf(v.y); o.z = f2bf(v.z); o.w = f2bf(v.w);
    ((ushort4*)out)[i] = o;
}

// ---------- 256x256 8-phase GEMM  C[M,N] = A[M,K] * B[N,K]^T (bf16 in, fp32 acc) ----
// Geometry: BM=BN=256, BK=64, 8 waves (2M x 4N), per-wave out 128x64.
// LDS 128 KiB: buf b at b*65536; A tile (256x64 bf16, 32 KB) at +0, B at +32768.
// Staged with linear LDS dest + inverse-swizzled (involution) global source;
// fragments read at swizzled addresses.
// Stage schedule (iter i computes t0=2i from buf0 p1-4, t1=2i+1 from buf1 p5-8):
//   p1: A-h0(t1->buf1)   [buf1-A last read prev p7, retired by prev p7-end bar]
//   p2: A-h1(t1->buf1)
//   p3: B-h0(t0+2->buf0) [buf0-B read p1/p2, retired by p2-end bar]
//   p4: B-h1(t0+2->buf0)
//   p5: A-h0(t0+2->buf0) [buf0-A read p1/p3, retired by p3-end bar]
//   p6: A-h1(t0+2->buf0)
//   p7: B-h0(t1+2->buf1) [buf1-B read p5/p6, retired by p6-end bar]
//   p8: B-h1(t1+2->buf1)
// vmcnt(4) before p4-end barrier => t1 fully landed before p5 reads.
// vmcnt(4) before p8-end barrier => t0+2 fully landed before next p1 reads.
// Last iteration: p1/p2 stage only, vmcnt(0) at p4, nothing at p8.
template <bool OUT_BF16>
__global__ __launch_bounds__(512, 2) void gemm256(const unsigned short* __restrict__ A,
                                                  const unsigned short* __restrict__ B,
                                                  void* __restrict__ Cv,
                                                  int M, int N, int K, int NBN) {
    __shared__ __align__(16) char smem[131072];
    const int tid = threadIdx.x;
    const int lane = tid & 63, wv = tid >> 6;
    const int wm = wv >> 2, wn = wv & 3;
    const int fr = lane & 15, fo = (lane >> 4) * 8;

    // bijective XCD swizzle (m204)
    const int nwg = gridDim.x, bid = blockIdx.x;
    const int q = nwg >> 3, r = nwg & 7, xcd = bid & 7, lid = bid >> 3;
    const int wg = (xcd < r ? xcd * (q + 1) : r * (q + 1) + (xcd - r) * q) + lid;
    const int bm = wg / NBN, bn = wg % NBN;

    const unsigned short* gA = A + (size_t)bm * 256 * K;
    const unsigned short* gB = B + (size_t)bn * 256 * K;

    // staging geometry: linear LDS dest o -> global element at swz(o)
    int srow[2][2], scol[2][2];
#pragma unroll
    for (int h = 0; h < 2; ++h)
#pragma unroll
        for (int rr = 0; rr < 2; ++rr) {
            int o = h * 16384 + rr * 8192 + tid * 16;
            int osw = swz(o);
            srow[h][rr] = osw >> 7;
            scol[h][rr] = (osw & 127) >> 1;
        }

    f32x4 acc[8][4] = {};
    short8 a[4][2], b[4][2];

    auto STAGE = [&](const unsigned short* g, int regionBase, int h, int t) {
#pragma unroll
        for (int rr = 0; rr < 2; ++rr)
            load_lds16(g + (size_t)srow[h][rr] * K + t * 64 + scol[h][rr],
                       smem + regionBase + h * 16384 + rr * 8192 + tid * 16);
    };
    auto RDA = [&](int bufBase, int mh) {
#pragma unroll
        for (int mf = 0; mf < 4; ++mf)
#pragma unroll
            for (int ks = 0; ks < 2; ++ks) {
                int o = swz((wm * 128 + mh * 64 + mf * 16 + fr) * 128 + (ks * 32 + fo) * 2);
                a[mf][ks] = *(const short8*)(smem + bufBase + o);
            }
    };
    auto RDB = [&](int bufBase, int nh) {
#pragma unroll
        for (int jj = 0; jj < 2; ++jj)
#pragma unroll
            for (int ks = 0; ks < 2; ++ks) {
                int o = swz((wn * 64 + (nh * 2 + jj) * 16 + fr) * 128 + (ks * 32 + fo) * 2);
                b[nh * 2 + jj][ks] = *(const short8*)(smem + bufBase + 32768 + o);
            }
    };
    auto MM = [&](int mh, int nh) {
        __builtin_amdgcn_s_setprio(1);
#pragma unroll
        for (int mf = 0; mf < 4; ++mf)
#pragma unroll
            for (int jj = 0; jj < 2; ++jj)
#pragma unroll
                for (int ks = 0; ks < 2; ++ks)
                    acc[mh * 4 + mf][nh * 2 + jj] = __builtin_amdgcn_mfma_f32_16x16x32_bf16(
                        a[mf][ks], b[nh * 2 + jj][ks], acc[mh * 4 + mf][nh * 2 + jj], 0, 0, 0);
        __builtin_amdgcn_s_setprio(0);
    };

    // region byte bases
    const int A0 = 0, B0 = 32768, A1 = 65536, B1 = 98304;

    // prologue: tile0 full into buf0, tile1 B-halves into buf1
    STAGE(gA, A0, 0, 0); STAGE(gA, A0, 1, 0);
    STAGE(gB, B0, 0, 0); STAGE(gB, B0, 1, 0);
    STAGE(gB, B1, 0, 1); STAGE(gB, B1, 1, 1);
    FENCE();
    asm volatile("s_waitcnt vmcnt(4)" ::: "memory");
    __builtin_amdgcn_s_barrier();
    FENCE();

    const int NIT = K >> 7;  // K/128, K%128==0
    for (int i = 0; i < NIT; ++i) {
        const bool last = (i == NIT - 1);
        const int t0 = 2 * i, t1 = 2 * i + 1;
        // P1
        RDA(A0, 0); RDB(A0, 0);
        STAGE(gA, A1, 0, t1);
        BAR(); MM(0, 0); BAR();
        // P2
        RDB(A0, 1);
        STAGE(gA, A1, 1, t1);
        BAR(); MM(0, 1); BAR();
        // P3
        RDA(A0, 1);
        if (!last) STAGE(gB, B0, 0, t0 + 2);
        BAR(); MM(1, 1); BAR();
        // P4
        if (!last) STAGE(gB, B0, 1, t0 + 2);
        BAR(); MM(1, 0);
        FENCE();
        if (last) asm volatile("s_waitcnt vmcnt(0)" ::: "memory");
        else      asm volatile("s_waitcnt vmcnt(4)" ::: "memory");
        __builtin_amdgcn_s_barrier();
        FENCE();
        // P5
        RDA(A1, 0); RDB(A1, 0);
        if (!last) STAGE(gA, A0, 0, t0 + 2);
        BAR(); MM(0, 0); BAR();
        // P6
        RDB(A1, 1);
        if (!last) STAGE(gA, A0, 1, t0 + 2);
        BAR(); MM(0, 1); BAR();
        // P7
        RDA(A1, 1);
        if (!last) STAGE(gB, B1, 0, t1 + 2);
        BAR(); MM(1, 1); BAR();
        // P8
        if (!last) STAGE(gB, B1, 1, t1 + 2);
        BAR(); MM(1, 0);
        FENCE();
        if (!last) asm volatile("s_waitcnt vmcnt(4)" ::: "memory");
        __builtin_amdgcn_s_barrier();
        FENCE();
    }

    // epilogue
    const size_t row0 = (size_t)bm * 256 + wm * 128 + ((lane >> 4) << 2);
    const int col0 = bn * 256 + wn * 64 + fr;
#pragma unroll
    for (int mf = 0; mf < 8; ++mf)
#pragma unroll
        for (int nf = 0; nf < 4; ++nf)
#pragma unroll
            for (int j = 0; j < 4; ++j) {
                size_t idx = (row0 + mf * 16 + j) * (size_t)N + col0 + nf * 16;
                if (OUT_BF16) ((unsigned short*)Cv)[idx] = f2bf(acc[mf][nf][j]);
                else          ((float*)Cv)[idx] = acc[mf][nf][j];
            }
}

// ---------- RoPE (interleaved, first 64 dims) + repack q,k -> [b,h,s,d] ----------
__global__ __launch_bounds__(256) void rope_repack(const unsigned short* __restrict__ qkv,
                                                   const int* __restrict__ positions,
                                                   unsigned short* __restrict__ qp,
                                                   unsigned short* __restrict__ kp) {
    int r = blockIdx.x * 4 + (threadIdx.x >> 6);   // (b,s,h) row, 0..65535
    int h = r & 15, s = (r >> 4) & 2047, b = r >> 15;
    int d = (threadIdx.x & 63) * 4;
    const unsigned short* src = qkv + (size_t)(b * 2048 + s) * 12288 + h * 256 + d;
    ushort4 q = *(const ushort4*)src;
    ushort4 k = *(const ushort4*)(src + 4096);
    if (d < 64) {
        float pos = (float)positions[s];
        const float LF = 0.4152410118609203f;      // log2(10000)/32
        float i0 = (float)(d >> 1);
        float a0 = pos * exp2f(-i0 * LF);
        float a1 = pos * exp2f(-(i0 + 1.0f) * LF);
        float c0 = cosf(a0), s0 = sinf(a0), c1 = cosf(a1), s1 = sinf(a1);
        float qx = bf2f(q.x), qy = bf2f(q.y), qz = bf2f(q.z), qw = bf2f(q.w);
        q.x = f2bf(qx * c0 - qy * s0); q.y = f2bf(qx * s0 + qy * c0);
        q.z = f2bf(qz * c1 - qw * s1); q.w = f2bf(qz * s1 + qw * c1);
        float kx = bf2f(k.x), ky = bf2f(k.y), kz = bf2f(k.z), kw = bf2f(k.w);
        k.x = f2bf(kx * c0 - ky * s0); k.y = f2bf(kx * s0 + ky * c0);
        k.z = f2bf(kz * c1 - kw * s1); k.w = f2bf(kz * s1 + kw * c1);
    }
    size_t dst = ((size_t)((b * 16 + h) * 2048 + s)) * 256 + d;
    *(ushort4*)&qp[dst] = q;
    *(ushort4*)&kp[dst] = k;
}

// ---------- V transpose -> [b,h,d,s] ----------
__global__ __launch_bounds__(256) void v_transpose(const unsigned short* __restrict__ qkv,
                                                   unsigned short* __restrict__ vt) {
    int bid = blockIdx.x;
    int dt = bid & 3, st = (bid >> 2) & 31, bh = bid >> 7;
    int b = bh >> 4, h = bh & 15;
    __shared__ unsigned short t[64][72];
    int tid = threadIdx.x;
#pragma unroll
    for (int rep = 0; rep < 16; ++rep) {
        int idx = rep * 256 + tid;
        int r = idx >> 6, c = idx & 63;   // r: s-offset, c: d-offset
        t[r][c] = qkv[(size_t)(b * 2048 + st * 64 + r) * 12288 + 8192 + h * 256 + dt * 64 + c];
    }
    __syncthreads();
#pragma unroll
    for (int rep = 0; rep < 16; ++rep) {
        int idx = rep * 256 + tid;
        int r = idx >> 6, c = idx & 63;   // r: d-offset, c: s-offset
        vt[(size_t)(bh * 256 + dt * 64 + r) * 2048 + st * 64 + c] = t[c][r];
    }
}

// ---------- flash attention (causal), 4 waves x 16 q-rows, KV tile 32 ----------
__global__ __launch_bounds__(256) void attn_fwd(const unsigned short* __restrict__ Qp,
                                                const unsigned short* __restrict__ Kp,
                                                const unsigned short* __restrict__ Vt,
                                                unsigned short* __restrict__ Oa) {
    __shared__ __align__(16) unsigned short Ks[32 * 256];
    __shared__ __align__(16) unsigned short Vs[256 * 32];
    __shared__ __align__(16) unsigned short Ps[4][16 * 32];
    const int tid = threadIdx.x, lane = tid & 63, wv = tid >> 6;
    const int bh = blockIdx.x, qt = blockIdx.y;
    const int fr = lane & 15, fo = (lane >> 4) * 8;
    const unsigned short* Qb = Qp + (size_t)bh * 2048 * 256;
    const unsigned short* Kb = Kp + (size_t)bh * 2048 * 256;
    const unsigned short* Vb = Vt + (size_t)bh * 256 * 2048;
    const int qbase = qt * 64 + wv * 16;

    short8 qf[8];
#pragma unroll
    for (int c = 0; c < 8; ++c)
        qf[c] = *(const short8*)&Qb[(size_t)(qbase + fr) * 256 + c * 32 + fo];

    f32x4 o_acc[16] = {};
    float m_run[4] = {-1e30f, -1e30f, -1e30f, -1e30f};
    float l_run[4] = {0.f, 0.f, 0.f, 0.f};

    const int nkv = qt * 64 + 64;
    for (int kv0 = 0; kv0 < nkv; kv0 += 32) {
#pragma unroll
        for (int i = 0; i < 4; ++i) {
            int eb = (wv * 4 + i) * 512;
            load_lds16(&Kb[(size_t)(kv0 + (eb >> 8) + (lane >> 5)) * 256 + (lane & 31) * 8], &Ks[eb]);
        }
#pragma unroll
        for (int i = 0; i < 4; ++i) {
            int eb = (wv * 4 + i) * 512;
            load_lds16(&Vb[(size_t)((eb >> 5) + (lane >> 2)) * 2048 + kv0 + (lane & 3) * 8], &Vs[eb]);
        }
        __syncthreads();

        f32x4 sc[2] = {};
#pragma unroll
        for (int t = 0; t < 2; ++t)
#pragma unroll
            for (int c = 0; c < 8; ++c) {
                short8 kf = *(const short8*)&Ks[(t * 16 + fr) * 256 + c * 32 + fo];
                sc[t] = __builtin_amdgcn_mfma_f32_16x16x32_bf16(qf[c], kf, sc[t], 0, 0, 0);
            }

        float sv[2][4];
#pragma unroll
        for (int j = 0; j < 4; ++j) {
            int qi = qbase + ((lane >> 4) << 2) + j;
#pragma unroll
            for (int t = 0; t < 2; ++t) {
                float x = sc[t][j] * 0.0625f;
                int kvi = kv0 + t * 16 + fr;
                sv[t][j] = (kvi > qi) ? -1e30f : x;
            }
            float pm = fmaxf(sv[0][j], sv[1][j]);
#pragma unroll
            for (int off = 1; off < 16; off <<= 1)
                pm = fmaxf(pm, __shfl_xor(pm, off));
            float mn = fmaxf(m_run[j], pm);
            float al = __expf(m_run[j] - mn);
            m_run[j] = mn;
            float rs = 0.f;
#pragma unroll
            for (int t = 0; t < 2; ++t) {
                float p = __expf(sv[t][j] - mn);
                rs += p;
                Ps[wv][(((lane >> 4) << 2) + j) * 32 + t * 16 + fr] = f2bf(p);
            }
#pragma unroll
            for (int off = 1; off < 16; off <<= 1)
                rs += __shfl_xor(rs, off);
            l_run[j] = l_run[j] * al + rs;
#pragma unroll
            for (int n = 0; n < 16; ++n) o_acc[n][j] *= al;
        }

        short8 pf = *(const short8*)&Ps[wv][fr * 32 + fo];
#pragma unroll
        for (int n = 0; n < 16; ++n) {
            short8 vf = *(const short8*)&Vs[(n * 16 + fr) * 32 + fo];
            o_acc[n] = __builtin_amdgcn_mfma_f32_16x16x32_bf16(pf, vf, o_acc[n], 0, 0, 0);
        }
        __syncthreads();
    }

    const int b = bh >> 4, h = bh & 15;
#pragma unroll
    for (int j = 0; j < 4; ++j) {
        float inv = 1.0f / l_run[j];
        int qrow = qbase + ((lane >> 4) << 2) + j;
        size_t base = ((size_t)(b * 2048 + qrow)) * 4096 + h * 256;
#pragma unroll
        for (int n = 0; n < 16; ++n)
            Oa[base + n * 16 + fr] = f2bf(o_acc[n][j] * inv);
    }
}

// ---------- launch ----------
extern "C" void kernel_launch(void* const* d_in, const int* in_sizes, int n_in,
                              void* d_out, int out_size, void* d_ws, size_t ws_size,
                              hipStream_t stream) {
    const float* hidden = (const float*)d_in[0];
    const int* positions = (const int*)d_in[1];
    const float* w_qkv = (const float*)d_in[2];
    const float* w_out = (const float*)d_in[3];
    float* out = (float*)d_out;

    const size_t MB32 = 33554432;   // 32 MiB
    char* ws = (char*)d_ws;
    unsigned short* hidden_bf = (unsigned short*)ws;              // 32 MB; later attn out
    unsigned short* wqkv_bf   = (unsigned short*)(ws + MB32);     // 96 MB; later q/k/vt
    unsigned short* qkv_bf    = (unsigned short*)(ws + 4 * MB32); // 96 MB; later wout_bf
    unsigned short* qp  = wqkv_bf;                                // 32 MB
    unsigned short* kp  = wqkv_bf + 16777216;                     // 32 MB
    unsigned short* vtp = wqkv_bf + 33554432;                     // 32 MB
    unsigned short* attn_bf = hidden_bf;                          // 32 MB (reuse)
    unsigned short* wout_bf = qkv_bf;                             // 32 MB (reuse)

    // 1. convert hidden (16.7M) and w_qkv (50.3M) to bf16
    conv_bf16<<<16384, 256, 0, stream>>>(hidden, hidden_bf, 4194304);
    conv_bf16<<<49152, 256, 0, stream>>>(w_qkv, wqkv_bf, 12582912);

    // 2. qkv = hidden @ w_qkv^T   (M=4096, N=12288, K=4096), bf16 out
    gemm256<true><<<16 * 48, 512, 0, stream>>>(hidden_bf, wqkv_bf, qkv_bf, 4096, 12288, 4096, 48);

    // 3. RoPE + repack q,k ; transpose v
    rope_repack<<<16384, 256, 0, stream>>>(qkv_bf, positions, qp, kp);
    v_transpose<<<4096, 256, 0, stream>>>(qkv_bf, vtp);

    // 4. causal flash attention -> attn_bf [4096, 4096]
    attn_fwd<<<dim3(32, 32), 256, 0, stream>>>(qp, kp, vtp, attn_bf);

    // 5. convert w_out, final projection (fp32 out)
    conv_bf16<<<16384, 256, 0, stream>>>(w_out, wout_bf, 4194304);
    gemm256<false><<<16 * 16, 512, 0, stream>>>(attn_bf, wout_bf, out, 4096, 4096, 4096, 16);
}